// Round 7
// baseline (557.507 us; speedup 1.0000x reference)
//
#include <hip/hip_runtime.h>
#include <hip/hip_bf16.h>

#define B_     16
#define CIN_   512
#define COUT_  512
#define RES_   64
#define WDIM_  512
#define LRELU_A 0.2f
#define GAIN_  1.4142135623730951f

typedef __attribute__((ext_vector_type(8)))  __bf16 bf16x8;
typedef __attribute__((ext_vector_type(16))) float  f32x16;
typedef __attribute__((ext_vector_type(4)))  int    int4v;
typedef __attribute__((ext_vector_type(8)))  unsigned short u16x8;

__device__ __forceinline__ unsigned short f2bf(float f) {
    union { float f; unsigned int u; } v; v.f = f;
    unsigned int u = v.u;
    return (unsigned short)((u + 0x7FFFu + ((u >> 16) & 1u)) >> 16);  // RNE
}

// async global->LDS, 16B per lane; LDS dest = wave-uniform base (HW adds lane*16)
__device__ __forceinline__ void gl_lds16(const void* g, void* l) {
    __builtin_amdgcn_global_load_lds(
        (const __attribute__((address_space(1))) unsigned int*)g,
        (__attribute__((address_space(3))) unsigned int*)l, 16, 0, 0);
}

// ---------------- K1: styles = w @ (affine_w^T / sqrt(512)) + affine_b ----------------
__global__ void styles_k(const float* __restrict__ w, const float* __restrict__ aw,
                         const float* __restrict__ ab, float* __restrict__ styles) {
    int idx = blockIdx.x * 256 + threadIdx.x;      // 8192 = b*512 + ci
    int b = idx >> 9, ci = idx & 511;
    const float4* wp = (const float4*)(w + b * WDIM_);
    const float4* ap = (const float4*)(aw + (size_t)ci * WDIM_);
    float acc = 0.f;
    #pragma unroll 4
    for (int k = 0; k < WDIM_ / 4; ++k) {
        float4 a = ap[k], q = wp[k];
        acc += a.x * q.x + a.y * q.y + a.z * q.z + a.w * q.w;
    }
    styles[idx] = acc * 0.04419417382415922f + ab[ci];   // 1/sqrt(512)
}

// ---------------- K2a: wt_pack[cc][t][co][ci16] bf16 — coalesced 32B stores -------------
__global__ void wprep_wt(const float* __restrict__ weight, unsigned short* __restrict__ wt) {
    int blk = blockIdx.x;                // 288 = cc*9 + t
    int cc = blk / 9, t = blk % 9;
    int co = threadIdx.x;                // 512 threads
    const float* wp = weight + ((size_t)co * 512 + cc * 16) * 9 + t;
    u16x8 lo, hi;
    #pragma unroll
    for (int j = 0; j < 8; ++j) lo[j] = f2bf(wp[j * 9]);
    #pragma unroll
    for (int j = 0; j < 8; ++j) hi[j] = f2bf(wp[(j + 8) * 9]);
    unsigned short* o = wt + (((size_t)cc * 9 + t) * 512 + co) * 16;
    *(u16x8*)o = lo;
    *(u16x8*)(o + 8) = hi;
}

// ---------------- K2b: wsq[co][ci] = sum_t w^2 ------------------------------------------
__global__ void wsq_k(const float* __restrict__ weight, float* __restrict__ wsq) {
    int idx = blockIdx.x * 256 + threadIdx.x;      // 262144 = co*512 + ci
    const float* wp = weight + (size_t)idx * 9;
    float s = 0.f;
    #pragma unroll
    for (int t = 0; t < 9; ++t) { float f = wp[t]; s += f * f; }
    wsq[idx] = s;
}

// ---------------- K3: demod[b][co] = rsqrt(sum_ci wsq[co][ci]*styles[b][ci]^2 + 1e-8) ----
__global__ void demod_k(const float* __restrict__ styles, const float* __restrict__ wsq,
                        float* __restrict__ demod) {
    int idx = blockIdx.x * 256 + threadIdx.x;      // 8192 = b*512 + co
    int b = idx >> 9, co = idx & 511;
    const float4* wr = (const float4*)(wsq + (size_t)co * CIN_);
    const float4* sr = (const float4*)(styles + (size_t)b * CIN_);
    float acc = 0.f;
    #pragma unroll 4
    for (int ci = 0; ci < CIN_ / 4; ++ci) {
        float4 q = wr[ci], s = sr[ci];
        acc += q.x * s.x * s.x + q.y * s.y * s.y + q.z * s.z * s.z + q.w * s.w * s.w;
    }
    demod[idx] = rsqrtf(acc + 1e-8f);
}

// ------- K4: xs[b][rr][cc][w][ci16]; rr=0,65 zero halo; rr=1..64 = bf16(x*style) --------
__global__ void xprep_k(const float* __restrict__ x, const float* __restrict__ styles,
                        unsigned short* __restrict__ xs) {
    __shared__ float tile[64][68];         // pad 68: 16B-aligned float4 writes, spread banks
    __shared__ float styv[64];
    int bid = blockIdx.x;                  // 8448 = b*528 + rr*8 + ct
    int ct = bid & 7, rr = (bid >> 3) % 66, b = bid / 528;
    int tid = threadIdx.x;
    unsigned short* xo = xs + (size_t)(b * 66 + rr) * 32768 + (size_t)ct * 4096;
    if (rr == 0 || rr == 65) {             // halo rows: zeros
        u16x8 z = {0, 0, 0, 0, 0, 0, 0, 0};
        #pragma unroll
        for (int it = 0; it < 2; ++it) {
            int s = it * 256 + tid;
            int ccl = s >> 7, w = (s >> 1) & 63, half = s & 1;
            *(u16x8*)(xo + ccl * 1024 + w * 16 + half * 8) = z;
        }
        return;
    }
    int h = rr - 1;
    if (tid < 64) styv[tid] = styles[b * CIN_ + ct * 64 + tid];
    const float* xp = x + (((size_t)(b * CIN_ + ct * 64)) * RES_ + h) * RES_;
    #pragma unroll
    for (int it = 0; it < 4; ++it) {
        int ci = it * 16 + (tid >> 4);
        int w4 = (tid & 15) * 4;
        float4 v = *(const float4*)(xp + (size_t)ci * (RES_ * RES_) + w4);
        *(float4*)&tile[ci][w4] = v;
    }
    __syncthreads();
    #pragma unroll
    for (int it = 0; it < 2; ++it) {
        int s = it * 256 + tid;                // contiguous 8-short runs
        int ccl = s >> 7, w = (s >> 1) & 63, half = s & 1;
        int ci0 = ccl * 16 + half * 8;
        u16x8 v;
        #pragma unroll
        for (int j = 0; j < 8; ++j) v[j] = f2bf(tile[ci0 + j][w] * styv[ci0 + j]);
        *(u16x8*)(xo + ccl * 1024 + w * 16 + half * 8) = v;
    }
}

// ---- K5: main conv. block 128 co x 256 px (4 rows); wave = 64 co x 128 px; CK=16 --------
// W from global (register dbuf af[2]); LDS holds only X (dbuf). Counted-vmcnt barriers.
#define XBUF 12672                 // 6 rows * 132 chunks * 16B

#define LOADAF(SLOT, CC, DY) do {                                            \
    const char* p_ = wb_ + (size_t)((CC) * 9 + (DY) * 3) * 16384;            \
    _Pragma("unroll") for (int tt_ = 0; tt_ < 3; ++tt_)                      \
      _Pragma("unroll") for (int mt_ = 0; mt_ < 2; ++mt_)                    \
        af[SLOT][tt_][mt_] = *(const bf16x8*)(p_ + tt_ * 16384 + mt_ * 1024);\
  } while (0)

// counted barrier: stageX already retired by older af-use waits; 6 af loads may fly
#define BARRIER6() do {                                                      \
    asm volatile("s_waitcnt vmcnt(6)" ::: "memory");                         \
    __builtin_amdgcn_s_barrier();                                            \
    __builtin_amdgcn_sched_barrier(0);                                       \
  } while (0)

#define PHASE(CC, DY, SLOT, LG, LSLOT, LCC, LDY, XG, XCC, XBI) do {          \
    const char* Xb_ = Xl + ((CC) & 1) * XBUF;                                \
    bf16x8 bv[3][4];                                                         \
    _Pragma("unroll") for (int tt_ = 0; tt_ < 3; ++tt_)                      \
      _Pragma("unroll") for (int nt_ = 0; nt_ < 4; ++nt_) {                  \
        int o_ = (((nt_ & 1) * 32) + l31 + tt_) * 32 + (kg << 4);            \
        bv[tt_][nt_] = *(const bf16x8*)(Xb_ + (rp * 2 + (nt_ >> 1) + (DY)) * 2112 + o_); \
      }                                                                      \
    if (LG) { LOADAF(LSLOT, LCC, LDY); }                                     \
    if (XG) { stageX(XCC, XBI); }                                            \
    __builtin_amdgcn_s_setprio(1);                                           \
    _Pragma("unroll") for (int tt_ = 0; tt_ < 3; ++tt_)                      \
      _Pragma("unroll") for (int mt_ = 0; mt_ < 2; ++mt_)                    \
        _Pragma("unroll") for (int nt_ = 0; nt_ < 4; ++nt_)                  \
          acc[mt_][nt_] = __builtin_amdgcn_mfma_f32_32x32x16_bf16(           \
              af[SLOT][tt_][mt_], bv[tt_][nt_], acc[mt_][nt_], 0, 0, 0);     \
    __builtin_amdgcn_s_setprio(0);                                           \
  } while (0)

__global__ __launch_bounds__(256, 2) void conv_k(
    const unsigned short* __restrict__ xs, const unsigned short* __restrict__ wt,
    const float* __restrict__ demod, const float* __restrict__ bias,
    const float* __restrict__ noise, const float* __restrict__ nsp,
    float* __restrict__ out)
{
    __shared__ __align__(16) char Xl[2 * XBUF];

    const int tid  = threadIdx.x;
    const int lane = tid & 63;
    const int wid  = tid >> 6;         // 0..3
    const int l31  = lane & 31;
    const int kg   = lane >> 5;
    const int ch   = wid & 1;          // co-half (64 co)
    const int rp   = wid >> 1;         // row-pair (2 rows)

    // XCD swizzle: 1024 blocks; all blocks on an XCD share the same W co-panel m
    const int lb = ((blockIdx.x & 7) << 7) | (blockIdx.x >> 3);
    const int m  = lb >> 8;            // 0..3
    const int rest = lb & 255;
    const int b  = rest >> 4;
    const int h0 = (rest & 15) * 4;

    // zero column-halo chunks (0,1,130,131 of each of 6 rows, both X buffers)
    if (tid < 48) {
        int buf = tid / 24, rem = tid % 24, r = rem >> 2, k = rem & 3;
        int chunk = r * 132 + (k < 2 ? k : 128 + k);
        int4v z = {0, 0, 0, 0};
        *(int4v*)(Xl + buf * XBUF + chunk * 16) = z;
    }

    const char* xsrc = (const char*)xs + (size_t)(b * 66 + h0) * 65536;
    auto stageX = [&](int cc, int buf) {           // 768 chunks, 3 gl_lds16/lane
        const char* s0 = xsrc + cc * 2048;         // [row][cc][w][ci16]
        char* d0 = Xl + buf * XBUF;
        #pragma unroll
        for (int k = 0; k < 3; ++k) {
            const int c0 = k * 256 + (wid << 6);   // wave-uniform
            const int r  = c0 >> 7;                // row 0..5, uniform within wave
            gl_lds16(s0 + (size_t)r * 65536 + (size_t)((c0 + lane) & 127) * 16,
                     d0 + (r * 132 + ((c0 & 127) + 2)) * 16);
        }
    };

    // per-thread W fragment base (A-operand: row = co = ...+l31, k-half = kg)
    const char* wb_ = (const char*)wt
        + (size_t)((m * 128 + ch * 64 + l31) * 32 + kg * 16);

    f32x16 acc[2][4];
    #pragma unroll
    for (int mt = 0; mt < 2; ++mt)
        #pragma unroll
        for (int nt = 0; nt < 4; ++nt)
            #pragma unroll
            for (int j = 0; j < 16; ++j) acc[mt][nt][j] = 0.f;

    bf16x8 af[2][3][2];                 // [slot][dx][mt] register W dbuf

    // prologue: X0 (oldest), then P0E's af; halo ds-writes must land before barrier
    stageX(0, 0);
    LOADAF(0, 0, 0);
    asm volatile("s_waitcnt vmcnt(6) lgkmcnt(0)" ::: "memory");
    __builtin_amdgcn_s_barrier();
    __builtin_amdgcn_sched_barrier(0);

    for (int pb = 0; pb < 16; ++pb) {
        const int ccE = pb * 2, ccO = ccE + 1;
        const bool nx = (pb < 15);
        //     CC   DY SLOT  LG   LSLOT LCC    LDY   XG     XCC     XBI
        PHASE(ccE,  0, 0,   true, 1,   ccE,    1,   true,   ccO,    1);
        PHASE(ccE,  1, 1,   true, 0,   ccE,    2,   false,  0,      0);
        PHASE(ccE,  2, 0,   true, 1,   ccO,    0,   false,  0,      0);
        BARRIER6();                                  // X(ccO) visible in buf1
        PHASE(ccO,  0, 1,   true, 0,   ccO,    1,   nx,     ccE+2,  0);
        PHASE(ccO,  1, 0,   true, 1,   ccO,    2,   false,  0,      0);
        PHASE(ccO,  2, 1,   nx,   0,   ccE+2,  0,   false,  0,      0);
        if (nx) BARRIER6();                          // X(ccE+2) visible in buf0
    }

    // epilogue: demod, noise, bias, lrelu*gain
    const float nsv = nsp[0];
    float nz[4];
    #pragma unroll
    for (int nt = 0; nt < 4; ++nt)
        nz[nt] = noise[(h0 + rp * 2 + (nt >> 1)) * 64 + (nt & 1) * 32 + l31] * nsv;
    #pragma unroll
    for (int mt = 0; mt < 2; ++mt) {
        #pragma unroll
        for (int j = 0; j < 16; ++j) {
            // C/D layout (verified m74/m101): col = lane&31, row = (j&3)+8*(j>>2)+4*kg
            int co = m * 128 + ch * 64 + mt * 32 + (j & 3) + 8 * (j >> 2) + 4 * kg;
            float d  = demod[b * COUT_ + co];
            float bs = bias[co];
            #pragma unroll
            for (int nt = 0; nt < 4; ++nt) {
                int h = h0 + rp * 2 + (nt >> 1);
                int w = (nt & 1) * 32 + l31;
                float v = acc[mt][nt][j] * d + nz[nt] + bs;
                v = (v >= 0.f ? v : LRELU_A * v) * GAIN_;
                out[((size_t)(b * COUT_ + co) * RES_ + h) * RES_ + w] = v;
            }
        }
    }
}

extern "C" void kernel_launch(void* const* d_in, const int* in_sizes, int n_in,
                              void* d_out, int out_size, void* d_ws, size_t ws_size,
                              hipStream_t stream) {
    const float* x    = (const float*)d_in[0];
    const float* w    = (const float*)d_in[1];
    const float* wgt  = (const float*)d_in[2];
    const float* bias = (const float*)d_in[3];
    const float* aw   = (const float*)d_in[4];
    const float* ab   = (const float*)d_in[5];
    const float* noi  = (const float*)d_in[6];
    const float* ns   = (const float*)d_in[7];
    float* out = (float*)d_out;

    char* ws = (char*)d_ws;
    float* styles        = (float*)(ws);                        // 32 KB
    float* demod         = (float*)(ws + 32768);                // 32 KB
    float* wsq           = (float*)(ws + 65536);                // 1 MB
    unsigned short* wt   = (unsigned short*)(ws + 1114112);     // 4.72 MB  [cc][t][co][ci16]
    unsigned short* xs   = (unsigned short*)(ws + 6291456);     // 69.2 MB  [b][66][cc][w][ci16]

    hipLaunchKernelGGL(styles_k, dim3(32),   dim3(256), 0, stream, w, aw, ab, styles);
    hipLaunchKernelGGL(wprep_wt, dim3(288),  dim3(512), 0, stream, wgt, wt);
    hipLaunchKernelGGL(wsq_k,    dim3(1024), dim3(256), 0, stream, wgt, wsq);
    hipLaunchKernelGGL(xprep_k,  dim3(8448), dim3(256), 0, stream, x, styles, xs);
    hipLaunchKernelGGL(demod_k,  dim3(32),   dim3(256), 0, stream, styles, wsq, demod);
    hipLaunchKernelGGL(conv_k,   dim3(1024), dim3(256), 0, stream,
                       xs, wt, demod, bias, noi, ns, out);
}